// Round 1
// 545.093 us; speedup vs baseline: 1.1517x; 1.1517x over previous
//
#include <hip/hip_runtime.h>
#include <cstdint>
#include <cstddef>

// ---------------------------------------------------------------------------
// AbsolutePositionalCrossAttention: B=16384, N=4, DIM=512, H=8, dh=64
//   1) transpose+cast weights -> WqkvT bf16 [1536][512], WoT bf16 [512][512]
//   2) cast x -> bf16;  q  = xbf @ WqT + bq   -> qkv[:, 0:512]
//   3) cast ctx -> bf16; kv = cbf @ WkvT + bkv -> qkv[:, 512:1536]
//   4) attention per batch (one wave = 8 heads), in-place into qkv[:, 0:512]
//   5) out = qkv[:,0:512] @ WoT + bo -> fp32 d_out
// GEMM: 128x128 tile, BK=64, global_load_lds(16B) staging, XOR-swizzled LDS
// chunks (conflict-free ds_read_b128), XCD-aware block swizzle for L2 reuse.
// ---------------------------------------------------------------------------

typedef __attribute__((ext_vector_type(8))) short short8;
typedef __attribute__((ext_vector_type(4))) float floatx4;

__device__ __forceinline__ unsigned short f2bf(float f) {
    unsigned u = __float_as_uint(f);
    unsigned r = 0x7fffu + ((u >> 16) & 1u);   // round-nearest-even
    return (unsigned short)((u + r) >> 16);
}
__device__ __forceinline__ float bf2f(unsigned short h) {
    return __uint_as_float(((unsigned)h) << 16);
}

__device__ __forceinline__ void async_cp16(const unsigned short* g, unsigned short* l) {
    __builtin_amdgcn_global_load_lds(
        (const __attribute__((address_space(1))) unsigned int*)g,
        (__attribute__((address_space(3))) unsigned int*)l, 16, 0, 0);
}

// ---- weight transpose + cast: in fp32 [K][N] row-major -> out bf16 [N][K] --
__global__ void transpose_cast_kernel(const float* __restrict__ in,
                                      unsigned short* __restrict__ out,
                                      int K, int N) {
    __shared__ float tile[32][33];
    const int kb = blockIdx.x * 32, nb = blockIdx.y * 32;
    const int t = threadIdx.x, c = t & 31, r = t >> 5;  // 256 threads
#pragma unroll
    for (int i = 0; i < 4; ++i) {
        int kl = r + 8 * i;
        tile[kl][c] = in[(size_t)(kb + kl) * N + nb + c];
    }
    __syncthreads();
#pragma unroll
    for (int i = 0; i < 4; ++i) {
        int nl = r + 8 * i;
        out[(size_t)(nb + nl) * K + kb + c] = f2bf(tile[c][nl]);
    }
}

// ---- fp32 -> bf16 cast, 8 elems/thread ------------------------------------
__global__ void cast_bf16_kernel(const float* __restrict__ in,
                                 unsigned short* __restrict__ out) {
    const int i = (int)blockIdx.x * 256 + threadIdx.x;
    float4 a = ((const float4*)in)[2 * i];
    float4 b = ((const float4*)in)[2 * i + 1];
    short8 p;
    p[0] = (short)f2bf(a.x); p[1] = (short)f2bf(a.y);
    p[2] = (short)f2bf(a.z); p[3] = (short)f2bf(a.w);
    p[4] = (short)f2bf(b.x); p[5] = (short)f2bf(b.y);
    p[6] = (short)f2bf(b.z); p[7] = (short)f2bf(b.w);
    ((short8*)out)[i] = p;
}

// ---- C[M][N] = A[M][K] @ Wt[N][K]^T + bias ---------------------------------
// grid (NXB, 512); NXB = 1<<xshift column blocks; 256 threads = 4 waves.
template <bool OUT_F32>
__global__ __launch_bounds__(256, 2)
void gemm_kernel(const unsigned short* __restrict__ A, int lda,
                 const unsigned short* __restrict__ Wt,   // bf16 [N][K]
                 const float* __restrict__ bias,          // fp32 [N-local]
                 void* __restrict__ Cv, int ldc,
                 int K, int xshift) {
    constexpr int BK = 64;
    __shared__ __align__(16) unsigned short As[128 * 64];
    __shared__ __align__(16) unsigned short Bs[128 * 64];
    const int t = threadIdx.x;
    const int wave = t >> 6, lane = t & 63;
    const int lm = lane & 15, quad = lane >> 4;

    // XCD swizzle: all column blocks of one row panel -> same XCD's L2.
    const int NXB = 1 << xshift;
    const int lin = (int)blockIdx.x + ((int)blockIdx.y << xshift);
    const int xcd = lin & 7, slot = lin >> 3;
    const int by = xcd * 64 + (slot >> xshift);   // gridDim.y == 512
    const int bx = slot & (NXB - 1);
    const int row0 = by * 128, n0 = bx * 128;
    const int wm = (wave & 1) * 64, wn = (wave >> 1) * 64;

    // staging: slot s = it*256 + t; row r = s>>3; chunk-slot = t&7;
    // fetch global chunk (slot ^ (r&7)) so LDS chunk c holds col (c ^ (r&7)).
    const int arow = t >> 3;                 // row within 32-row group
    const int cb = (t & 7) ^ (arow & 7);     // swizzled source chunk
    const unsigned short* Ag = A + (size_t)(row0 + arow) * lda + cb * 8;
    const unsigned short* Bg = Wt + (size_t)(n0 + arow) * K + cb * 8;

    floatx4 acc[4][4] = {};

    for (int kb = 0; kb < K; kb += BK) {
        __syncthreads();   // previous iteration's ds_reads done
#pragma unroll
        for (int it = 0; it < 4; ++it) {
            async_cp16(Ag + kb + (size_t)(it * 32) * lda,
                       &As[(it * 256 + wave * 64) * 8]);
            async_cp16(Bg + kb + (size_t)(it * 32) * K,
                       &Bs[(it * 256 + wave * 64) * 8]);
        }
        __syncthreads();   // drains vmcnt before barrier (compiler-emitted)
#pragma unroll
        for (int kk = 0; kk < 2; ++kk) {
            short8 af[4], bfv[4];
            const int cfrag = kk * 4 + quad;
            const int csw = cfrag ^ (lm & 7);   // r&7 == lm&7 for all frags
#pragma unroll
            for (int mi = 0; mi < 4; ++mi)
                af[mi] = *(const short8*)&As[(wm + mi * 16 + lm) * 64 + csw * 8];
#pragma unroll
            for (int ni = 0; ni < 4; ++ni)
                bfv[ni] = *(const short8*)&Bs[(wn + ni * 16 + lm) * 64 + csw * 8];
#pragma unroll
            for (int mi = 0; mi < 4; ++mi)
#pragma unroll
                for (int ni = 0; ni < 4; ++ni)
                    acc[mi][ni] = __builtin_amdgcn_mfma_f32_16x16x32_bf16(
                        af[mi], bfv[ni], acc[mi][ni], 0, 0, 0);
        }
    }
    // ---- epilogue: D lane layout col=lane&15, row=quad*4+r ----
#pragma unroll
    for (int ni = 0; ni < 4; ++ni) {
        int col = n0 + wn + ni * 16 + lm;
        float bv = bias[col];
#pragma unroll
        for (int mi = 0; mi < 4; ++mi) {
            int rowb = row0 + wm + mi * 16 + quad * 4;
#pragma unroll
            for (int r = 0; r < 4; ++r) {
                float v = acc[mi][ni][r] + bv;
                if (OUT_F32)
                    ((float*)Cv)[(size_t)(rowb + r) * ldc + col] = v;
                else
                    ((unsigned short*)Cv)[(size_t)(rowb + r) * ldc + col] = f2bf(v);
            }
        }
    }
}

// ---- attention: one WAVE per batch; 8 lanes per head, 8 dh elems per lane --
// qkv bf16 [65536][1536] = [q | k | v]; result overwrites q slots.
// For a fixed (row i, tensor), the wave's 64 lanes cover one contiguous
// 512-element segment -> 16 B/lane fully-coalesced dwordx4 loads/stores.
// Dot reduce = 3-step shfl_xor within each 8-lane head group.
__global__ __launch_bounds__(256)
void attn_kernel(unsigned short* __restrict__ qkv) {
    const int t = threadIdx.x;
    const int wave = t >> 6, lane = t & 63;
    const int b = (int)blockIdx.x * 4 + wave;     // one batch per wave
    const float scale = 0.044194173824159216f;    // 512^-0.5
    const size_t rowbase = (size_t)b * 4 * 1536 + lane * 8;

    short8 qv[4], kv8[4], vv[4];
#pragma unroll
    for (int i = 0; i < 4; ++i) {
        const size_t r = rowbase + (size_t)i * 1536;
        qv[i]  = *(const short8*)&qkv[r];
        kv8[i] = *(const short8*)&qkv[r + 512];
        vv[i]  = *(const short8*)&qkv[r + 1024];
    }
    float qf[4][8], kf[4][8];
#pragma unroll
    for (int i = 0; i < 4; ++i)
#pragma unroll
        for (int e = 0; e < 8; ++e) {
            qf[i][e] = bf2f((unsigned short)qv[i][e]);
            kf[i][e] = bf2f((unsigned short)kv8[i][e]);
        }

    // s[i][j] = scale * (q_i . k_j) over dh=64 (8 in-lane + 8-lane butterfly)
    float s[4][4];
#pragma unroll
    for (int i = 0; i < 4; ++i)
#pragma unroll
        for (int j = 0; j < 4; ++j) {
            float p = 0.f;
#pragma unroll
            for (int e = 0; e < 8; ++e) p += qf[i][e] * kf[j][e];
            p += __shfl_xor(p, 1, 64);
            p += __shfl_xor(p, 2, 64);
            p += __shfl_xor(p, 4, 64);
            s[i][j] = p * scale;
        }

    const float Mm[4][4] = {{1,1,1,0},{1,1,0,1},{1,0,1,1},{0,1,1,1}};
    const float Pp[4][4] = {{0,0,0,-1.6f},{0,0,-1.2f,0},{0,-0.8f,0,0},{-0.4f,0,0,0}};
    float w[4][4];
#pragma unroll
    for (int i = 0; i < 4; ++i) {
        float tj[4], mx = -1e30f;
#pragma unroll
        for (int j = 0; j < 4; ++j) {
            tj[j] = s[i][j] * Mm[i][j] + Pp[i][j];
            mx = fmaxf(mx, tj[j]);
        }
        float e[4], sum = 0.f;
#pragma unroll
        for (int j = 0; j < 4; ++j) { e[j] = __expf(tj[j] - mx); sum += e[j]; }
        float inv = 1.f / sum;
#pragma unroll
        for (int j = 0; j < 4; ++j) w[i][j] = e[j] * Mm[i][j] * inv;
    }

    // out_i = sum_j w[i][j] * v_j   (per-lane 8 dh elems), store to q slots
#pragma unroll
    for (int i = 0; i < 4; ++i) {
        float o[8] = {};
#pragma unroll
        for (int j = 0; j < 4; ++j) {
            const float wj = w[i][j];
#pragma unroll
            for (int e = 0; e < 8; ++e)
                o[e] += wj * bf2f((unsigned short)vv[j][e]);
        }
        short8 ov;
#pragma unroll
        for (int e = 0; e < 8; ++e) ov[e] = (short)f2bf(o[e]);
        *(short8*)&qkv[rowbase + (size_t)i * 1536] = ov;
    }
}

// ---------------------------------------------------------------------------
extern "C" void kernel_launch(void* const* d_in, const int* in_sizes, int n_in,
                              void* d_out, int out_size, void* d_ws, size_t ws_size,
                              hipStream_t stream) {
    const float* x   = (const float*)d_in[0];
    const float* ctx = (const float*)d_in[1];
    const float* Wq  = (const float*)d_in[2];
    const float* bq  = (const float*)d_in[3];
    const float* Wkv = (const float*)d_in[4];
    const float* bkv = (const float*)d_in[5];
    const float* Wo  = (const float*)d_in[6];
    const float* bo  = (const float*)d_in[7];
    float* out = (float*)d_out;

    const int M = 65536;  // B*N rows
    unsigned short* WqkvT = (unsigned short*)d_ws;          // 1536*512
    unsigned short* WoT   = WqkvT + 1536 * 512;             // 512*512
    unsigned short* abf   = WoT + 512 * 512;                // M*512 (x, then ctx)
    unsigned short* qkv   = abf + (size_t)M * 512;          // M*1536

    dim3 b256(256);
    transpose_cast_kernel<<<dim3(16, 16), b256, 0, stream>>>(Wq, WqkvT, 512, 512);
    transpose_cast_kernel<<<dim3(16, 32), b256, 0, stream>>>(Wkv, WqkvT + 512 * 512, 512, 1024);
    transpose_cast_kernel<<<dim3(16, 16), b256, 0, stream>>>(Wo, WoT, 512, 512);

    // q = xbf @ WqT + bq
    cast_bf16_kernel<<<dim3(M * 512 / (8 * 256)), b256, 0, stream>>>(x, abf);
    gemm_kernel<false><<<dim3(4, 512), b256, 0, stream>>>(
        abf, 512, WqkvT, bq, qkv, 1536, 512, 2);

    // kv = ctxbf @ WkvT + bkv (reuse abf after q-GEMM consumed it)
    cast_bf16_kernel<<<dim3(M * 512 / (8 * 256)), b256, 0, stream>>>(ctx, abf);
    gemm_kernel<false><<<dim3(8, 512), b256, 0, stream>>>(
        abf, 512, WqkvT + 512 * 512, bkv, qkv + 512, 1536, 512, 3);

    // one wave per batch: 16384 waves = 4096 blocks x 4 waves
    attn_kernel<<<dim3(16384 / 4), b256, 0, stream>>>(qkv);

    // out = attnout @ WoT + bo
    gemm_kernel<true><<<dim3(4, 512), b256, 0, stream>>>(
        qkv, 1536, WoT, bo, out, 512, 512, 2);
}